// Round 1
// baseline (3454.237 us; speedup 1.0000x reference)
//
#include <hip/hip_runtime.h>

// DescentPredictor: 50 SGD steps on y for E(x,y) = MLP([x;y]) energy.
// One persistent kernel: each block owns 32 rows for all 50 iterations.
// x-dependent part of layer0 (c = W0x@x + b0) computed once into registers.

typedef unsigned short u16;
typedef u16 u16x4 __attribute__((ext_vector_type(4)));
typedef u16 u16x8 __attribute__((ext_vector_type(8)));
typedef float f32x4 __attribute__((ext_vector_type(4)));
typedef __bf16 bf16x8 __attribute__((ext_vector_type(8)));

#define ITERS 50
#define EPSF 1e-5f
static constexpr float SCALE = 0.1f / 16384.0f;  // LR / B

__device__ __forceinline__ float bf2f(u16 h) {
  union { unsigned int u; float f; } v; v.u = ((unsigned int)h) << 16; return v.f;
}
__device__ __forceinline__ u16 f2bf(float f) {
  union { float f; unsigned int u; } v; v.f = f;
  unsigned int u = v.u;
  return (u16)((u + 0x7FFFu + ((u >> 16) & 1u)) >> 16);  // RNE
}
__device__ __forceinline__ f32x4 mfma16(u16x8 a, u16x8 b, f32x4 c) {
  return __builtin_amdgcn_mfma_f32_16x16x32_bf16(
      __builtin_bit_cast(bf16x8, a), __builtin_bit_cast(bf16x8, b), c, 0, 0, 0);
}

// ---------------- weight prep: f32 -> bf16 (+transposes) into ws -------------
// ws layout (bf16 elems): W0X[256][512] @0, W0Y[256][64] @131072,
// W0YT[64][256] @147456, W1[256][256] @163840, W1T @229376, W2 @294912, W2T @360448
__global__ void prep_weights(const float* __restrict__ W0, const float* __restrict__ W1,
                             const float* __restrict__ W2, u16* __restrict__ ws) {
  int i = blockIdx.x * 256 + threadIdx.x;
  if (i < 131072) {                 // W0X [256][512]
    ws[i] = f2bf(W0[(i >> 9) * 576 + (i & 511)]);
  } else if (i < 147456) {          // W0Y [256][64] = W0[:,512:576]
    int j = i - 131072;
    ws[i] = f2bf(W0[(j >> 6) * 576 + 512 + (j & 63)]);
  } else if (i < 163840) {          // W0YT [64][256]
    int j = i - 147456;
    ws[i] = f2bf(W0[(j & 255) * 576 + 512 + (j >> 8)]);
  } else if (i < 229376) {          // W1 [256][256]
    ws[i] = f2bf(W1[i - 163840]);
  } else if (i < 294912) {          // W1T
    int j = i - 229376;
    ws[i] = f2bf(W1[(j & 255) * 256 + (j >> 8)]);
  } else if (i < 360448) {          // W2
    ws[i] = f2bf(W2[i - 294912]);
  } else if (i < 425984) {          // W2T
    int j = i - 360448;
    ws[i] = f2bf(W2[(j & 255) * 256 + (j >> 8)]);
  }
}

// ---------------- GEMM helpers (per-wave: 2 Mtiles x 4 Ntiles of 16x16) ------
// A: LDS bf16 [32][AST], rows m. B: global bf16 [N][LDB] (row = output col, K contig).
template <int KS, int LDB, int AST>
__device__ __forceinline__ void gemm_big(const u16* At, const u16* __restrict__ Bg,
                                         f32x4 (&acc)[2][4], int w, int l15, int q) {
  const u16* Ab = At + l15 * AST + q * 8;
  const u16* Bb = Bg + (64 * w + l15) * LDB + q * 8;
#pragma unroll
  for (int ks = 0; ks < KS; ++ks) {
    u16x8 b[4];
#pragma unroll
    for (int j = 0; j < 4; ++j)
      b[j] = *(const u16x8*)(Bb + 16 * j * LDB + ks * 32);
#pragma unroll
    for (int i = 0; i < 2; ++i) {
      u16x8 a = *(const u16x8*)(Ab + 16 * i * AST + ks * 32);
#pragma unroll
      for (int j = 0; j < 4; ++j) acc[i][j] = mfma16(a, b[j], acc[i][j]);
    }
  }
}

// dy = dz0 @ W0y : out [32][64]; per-wave 1 Mtile x 2 Ntiles. BT = W0YT [64][256].
__device__ __forceinline__ void gemm_dy(const u16* At, const u16* __restrict__ BT,
                                        f32x4 (&dy)[2], int w, int l15, int q) {
  const int mi = w >> 1, nb = (w & 1) * 32;
  const u16* Ab = At + (mi * 16 + l15) * 264 + q * 8;
  const u16* B0 = BT + (nb + l15) * 256 + q * 8;
  const u16* B1 = BT + (nb + 16 + l15) * 256 + q * 8;
#pragma unroll
  for (int ks = 0; ks < 8; ++ks) {
    u16x8 a = *(const u16x8*)(Ab + ks * 32);
    dy[0] = mfma16(a, *(const u16x8*)(B0 + ks * 32), dy[0]);
    dy[1] = mfma16(a, *(const u16x8*)(B1 + ks * 32), dy[1]);
  }
}

// C/D layout: row = 4*q + reg, col = lane&15 (per tile).
__device__ __forceinline__ void epi_store(u16* dst, const f32x4 (&acc)[2][4], int w,
                                          int l15, int q) {
#pragma unroll
  for (int i = 0; i < 2; ++i)
#pragma unroll
    for (int j = 0; j < 4; ++j)
#pragma unroll
      for (int rr = 0; rr < 4; ++rr)
        dst[(16 * i + 4 * q + rr) * 264 + 64 * w + 16 * j + l15] = f2bf(acc[i][j][rr]);
}

// ---------------- elementwise passes (canonical: 8 threads/row, cols 32u+4cg+e)
__device__ __forceinline__ void ew_fwd(u16* zbuf, const float* bias, const float* g,
                                       const float* be, u16* aOut, float* invOut, int t) {
  const int r = t >> 3, cg = t & 7;
  u16* zp = zbuf + r * 264 + 4 * cg;
  u16* ap = aOut + r * 264 + 4 * cg;
  float z[32];
#pragma unroll
  for (int u = 0; u < 8; ++u) {
    u16x4 v = *(const u16x4*)(zp + 32 * u);
#pragma unroll
    for (int e = 0; e < 4; ++e) z[4 * u + e] = bf2f(v[e]);
  }
  if (bias) {
#pragma unroll
    for (int u = 0; u < 8; ++u) {
      f32x4 bv = *(const f32x4*)(bias + 32 * u + 4 * cg);
#pragma unroll
      for (int e = 0; e < 4; ++e) z[4 * u + e] += bv[e];
    }
  }
  float s = 0.f, ss = 0.f;
#pragma unroll
  for (int k = 0; k < 32; ++k) { s += z[k]; ss += z[k] * z[k]; }
  s += __shfl_xor(s, 1); ss += __shfl_xor(ss, 1);
  s += __shfl_xor(s, 2); ss += __shfl_xor(ss, 2);
  s += __shfl_xor(s, 4); ss += __shfl_xor(ss, 4);
  const float mu = s * (1.f / 256.f);
  const float var = ss * (1.f / 256.f) - mu * mu;
  const float inv = rsqrtf(var + EPSF);
  if ((t & 7) == 0) invOut[r] = inv;
#pragma unroll
  for (int u = 0; u < 8; ++u) {
    f32x4 gv = *(const f32x4*)(g + 32 * u + 4 * cg);
    f32x4 bev = *(const f32x4*)(be + 32 * u + 4 * cg);
    u16x4 zv, av;
#pragma unroll
    for (int e = 0; e < 4; ++e) {
      const int k = 4 * u + e;
      float zh = (z[k] - mu) * inv;
      zv[e] = f2bf(zh);
      float uu = zh * gv[e] + bev[e];
      float a = uu / (1.f + __expf(-uu));  // SiLU
      av[e] = f2bf(a);
    }
    *(u16x4*)(zp + 32 * u) = zv;   // zhat (for backward), in place
    *(u16x4*)(ap + 32 * u) = av;   // activation (next GEMM A)
  }
}

// layer2: fwd-LN + (da2 = Wout) + SiLU' + LN-backward fused; buf: z2 in, dz2 out.
__device__ __forceinline__ void ew_l2(u16* buf, const float* bias, const float* g,
                                      const float* be, const float* wo, int t) {
  const int r = t >> 3, cg = t & 7;
  u16* zp = buf + r * 264 + 4 * cg;
  float zh[32], dzh[32];
  float s = 0.f, ss = 0.f;
#pragma unroll
  for (int u = 0; u < 8; ++u) {
    u16x4 v = *(const u16x4*)(zp + 32 * u);
    f32x4 bv = *(const f32x4*)(bias + 32 * u + 4 * cg);
#pragma unroll
    for (int e = 0; e < 4; ++e) {
      float zz = bf2f(v[e]) + bv[e];
      zh[4 * u + e] = zz; s += zz; ss += zz * zz;
    }
  }
  s += __shfl_xor(s, 1); ss += __shfl_xor(ss, 1);
  s += __shfl_xor(s, 2); ss += __shfl_xor(ss, 2);
  s += __shfl_xor(s, 4); ss += __shfl_xor(ss, 4);
  const float mu = s * (1.f / 256.f);
  const float var = ss * (1.f / 256.f) - mu * mu;
  const float inv = rsqrtf(var + EPSF);
  float s1 = 0.f, s2 = 0.f;
#pragma unroll
  for (int u = 0; u < 8; ++u) {
    f32x4 gv = *(const f32x4*)(g + 32 * u + 4 * cg);
    f32x4 bev = *(const f32x4*)(be + 32 * u + 4 * cg);
    f32x4 wv = *(const f32x4*)(wo + 32 * u + 4 * cg);
#pragma unroll
    for (int e = 0; e < 4; ++e) {
      const int k = 4 * u + e;
      float zn = (zh[k] - mu) * inv;
      zh[k] = zn;
      float uu = zn * gv[e] + bev[e];
      float sg = 1.f / (1.f + __expf(-uu));
      float du = wv[e] * sg * (1.f + uu * (1.f - sg));  // da2 = Wout[col]
      float d = du * gv[e];
      dzh[k] = d; s1 += d; s2 += d * zn;
    }
  }
  s1 += __shfl_xor(s1, 1); s2 += __shfl_xor(s2, 1);
  s1 += __shfl_xor(s1, 2); s2 += __shfl_xor(s2, 2);
  s1 += __shfl_xor(s1, 4); s2 += __shfl_xor(s2, 4);
  const float m1 = s1 * (1.f / 256.f), m2 = s2 * (1.f / 256.f);
#pragma unroll
  for (int u = 0; u < 8; ++u) {
    u16x4 ov;
#pragma unroll
    for (int e = 0; e < 4; ++e) {
      const int k = 4 * u + e;
      ov[e] = f2bf(inv * (dzh[k] - m1 - zh[k] * m2));
    }
    *(u16x4*)(zp + 32 * u) = ov;
  }
}

// backward through SiLU+LN for layer l: gbuf has da in, dz out; zbuf has zhat.
__device__ __forceinline__ void ew_bwd(u16* gbuf, const u16* zbuf, const float* g,
                                       const float* be, const float* invArr, int t) {
  const int r = t >> 3, cg = t & 7;
  u16* dp = gbuf + r * 264 + 4 * cg;
  const u16* zp = zbuf + r * 264 + 4 * cg;
  const float inv = invArr[r];
  float zh[32], dzh[32];
  float s1 = 0.f, s2 = 0.f;
#pragma unroll
  for (int u = 0; u < 8; ++u) {
    u16x4 dv = *(const u16x4*)(dp + 32 * u);
    u16x4 zv = *(const u16x4*)(zp + 32 * u);
    f32x4 gv = *(const f32x4*)(g + 32 * u + 4 * cg);
    f32x4 bev = *(const f32x4*)(be + 32 * u + 4 * cg);
#pragma unroll
    for (int e = 0; e < 4; ++e) {
      const int k = 4 * u + e;
      float zn = bf2f(zv[e]);
      float da = bf2f(dv[e]);
      float uu = zn * gv[e] + bev[e];
      float sg = 1.f / (1.f + __expf(-uu));
      float du = da * sg * (1.f + uu * (1.f - sg));
      float d = du * gv[e];
      zh[k] = zn; dzh[k] = d; s1 += d; s2 += d * zn;
    }
  }
  s1 += __shfl_xor(s1, 1); s2 += __shfl_xor(s2, 1);
  s1 += __shfl_xor(s1, 2); s2 += __shfl_xor(s2, 2);
  s1 += __shfl_xor(s1, 4); s2 += __shfl_xor(s2, 4);
  const float m1 = s1 * (1.f / 256.f), m2 = s2 * (1.f / 256.f);
#pragma unroll
  for (int u = 0; u < 8; ++u) {
    u16x4 ov;
#pragma unroll
    for (int e = 0; e < 4; ++e) {
      const int k = 4 * u + e;
      ov[e] = f2bf(inv * (dzh[k] - m1 - zh[k] * m2));
    }
    *(u16x4*)(dp + 32 * u) = ov;
  }
}

// ---------------- main persistent kernel -------------------------------------
__global__ __launch_bounds__(256, 2) void descent_kernel(
    const float* __restrict__ x, const float* __restrict__ y0,
    const float* __restrict__ b0, const float* __restrict__ g0, const float* __restrict__ be0,
    const float* __restrict__ b1, const float* __restrict__ g1, const float* __restrict__ be1,
    const float* __restrict__ b2, const float* __restrict__ g2, const float* __restrict__ be2,
    const float* __restrict__ wout, const u16* __restrict__ ws, float* __restrict__ out) {
  __shared__ __align__(16) u16 zh0[32 * 264];   // zhat layer0 (also raw z0)
  __shared__ __align__(16) u16 zh1[32 * 264];   // zhat layer1 (also raw z1)
  __shared__ __align__(16) u16 aT[32 * 264];    // activation / gradient tile
  __shared__ __align__(16) u16 yb[32 * 72];     // y as bf16 (GEMM A input)
  __shared__ __align__(16) float params[9 * 256];  // g0 be0 g1 be1 g2 be2 b1 b2 wout
  __shared__ float invs[2][32];

  const int t = threadIdx.x;
  const int w = t >> 6, lane = t & 63, l15 = lane & 15, q = lane >> 4;
  const int rowbase = blockIdx.x * 32;

  const u16* W0X = ws;
  const u16* W0Y = ws + 131072;
  const u16* W0YT = ws + 147456;
  const u16* W1b = ws + 163840;
  const u16* W1T = ws + 229376;
  const u16* W2b = ws + 294912;
  const u16* W2T = ws + 360448;

  params[0 * 256 + t] = g0[t];  params[1 * 256 + t] = be0[t];
  params[2 * 256 + t] = g1[t];  params[3 * 256 + t] = be1[t];
  params[4 * 256 + t] = g2[t];  params[5 * 256 + t] = be2[t];
  params[6 * 256 + t] = b1[t];  params[7 * 256 + t] = b2[t];
  params[8 * 256 + t] = wout[t];

  // y master copy in registers, laid out as gemm_dy's C/D tiles.
  const int mi = w >> 1, nb = (w & 1) * 32;
  float yv[2][4];
#pragma unroll
  for (int j = 0; j < 2; ++j)
#pragma unroll
    for (int rr = 0; rr < 4; ++rr)
      yv[j][rr] = y0[(rowbase + mi * 16 + q * 4 + rr) * 64 + nb + 16 * j + l15];

  const f32x4 z4 = {0.f, 0.f, 0.f, 0.f};

  // Phase A: cR = x @ W0x^T + b0 (stays in registers, C/D layout of big GEMMs)
  f32x4 cR[2][4];
#pragma unroll
  for (int i = 0; i < 2; ++i)
#pragma unroll
    for (int j = 0; j < 4; ++j) cR[i][j] = z4;
  {
    const float* xp0 = x + (rowbase + l15) * 512 + q * 8;
    const u16* Bb = W0X + (64 * w + l15) * 512 + q * 8;
#pragma unroll 4
    for (int ks = 0; ks < 16; ++ks) {
      u16x8 b[4];
#pragma unroll
      for (int j = 0; j < 4; ++j) b[j] = *(const u16x8*)(Bb + 16 * j * 512 + ks * 32);
#pragma unroll
      for (int i = 0; i < 2; ++i) {
        const float* xp = xp0 + i * 16 * 512 + ks * 32;
        f32x4 x0 = *(const f32x4*)xp;
        f32x4 x1 = *(const f32x4*)(xp + 4);
        u16x8 a;
#pragma unroll
        for (int e = 0; e < 4; ++e) { a[e] = f2bf(x0[e]); a[4 + e] = f2bf(x1[e]); }
#pragma unroll
        for (int j = 0; j < 4; ++j) cR[i][j] = mfma16(a, b[j], cR[i][j]);
      }
    }
#pragma unroll
    for (int j = 0; j < 4; ++j) {
      float bb = b0[64 * w + 16 * j + l15];
#pragma unroll
      for (int i = 0; i < 2; ++i)
#pragma unroll
        for (int rr = 0; rr < 4; ++rr) cR[i][j][rr] += bb;
    }
  }
  __syncthreads();  // params ready

  for (int it = 0; it < ITERS; ++it) {
    // y -> bf16 tile
#pragma unroll
    for (int j = 0; j < 2; ++j)
#pragma unroll
      for (int rr = 0; rr < 4; ++rr)
        yb[(mi * 16 + q * 4 + rr) * 72 + nb + 16 * j + l15] = f2bf(yv[j][rr]);
    __syncthreads();

    f32x4 acc[2][4];
    // fwd layer0: z0 = c + y @ W0y^T
#pragma unroll
    for (int i = 0; i < 2; ++i)
#pragma unroll
      for (int j = 0; j < 4; ++j) acc[i][j] = cR[i][j];
    gemm_big<2, 64, 72>(yb, W0Y, acc, w, l15, q);
    epi_store(zh0, acc, w, l15, q);
    __syncthreads();
    ew_fwd(zh0, nullptr, &params[0 * 256], &params[1 * 256], aT, invs[0], t);
    __syncthreads();

    // fwd layer1
#pragma unroll
    for (int i = 0; i < 2; ++i)
#pragma unroll
      for (int j = 0; j < 4; ++j) acc[i][j] = z4;
    gemm_big<8, 256, 264>(aT, W1b, acc, w, l15, q);
    epi_store(zh1, acc, w, l15, q);
    __syncthreads();
    ew_fwd(zh1, &params[6 * 256], &params[2 * 256], &params[3 * 256], aT, invs[1], t);
    __syncthreads();

    // fwd layer2 (output overwrites aT after all reads complete)
#pragma unroll
    for (int i = 0; i < 2; ++i)
#pragma unroll
      for (int j = 0; j < 4; ++j) acc[i][j] = z4;
    gemm_big<8, 256, 264>(aT, W2b, acc, w, l15, q);
    __syncthreads();
    epi_store(aT, acc, w, l15, q);
    __syncthreads();
    ew_l2(aT, &params[7 * 256], &params[4 * 256], &params[5 * 256], &params[8 * 256], t);
    __syncthreads();

    // bwd layer2 GEMM: da1 = dz2 @ W2
#pragma unroll
    for (int i = 0; i < 2; ++i)
#pragma unroll
      for (int j = 0; j < 4; ++j) acc[i][j] = z4;
    gemm_big<8, 256, 264>(aT, W2T, acc, w, l15, q);
    __syncthreads();
    epi_store(aT, acc, w, l15, q);
    __syncthreads();
    ew_bwd(aT, zh1, &params[2 * 256], &params[3 * 256], invs[1], t);
    __syncthreads();

    // bwd layer1 GEMM: da0 = dz1 @ W1
#pragma unroll
    for (int i = 0; i < 2; ++i)
#pragma unroll
      for (int j = 0; j < 4; ++j) acc[i][j] = z4;
    gemm_big<8, 256, 264>(aT, W1T, acc, w, l15, q);
    __syncthreads();
    epi_store(aT, acc, w, l15, q);
    __syncthreads();
    ew_bwd(aT, zh0, &params[0 * 256], &params[1 * 256], invs[0], t);
    __syncthreads();

    // bwd layer0: dy = dz0 @ W0y ; y -= (LR/B) * dy
    f32x4 dy[2] = {z4, z4};
    gemm_dy(aT, W0YT, dy, w, l15, q);
#pragma unroll
    for (int j = 0; j < 2; ++j)
#pragma unroll
      for (int rr = 0; rr < 4; ++rr) yv[j][rr] -= SCALE * dy[j][rr];
    // next-iter yb write targets a different buffer; loop-head barrier orders it.
  }

#pragma unroll
  for (int j = 0; j < 2; ++j)
#pragma unroll
    for (int rr = 0; rr < 4; ++rr)
      out[(rowbase + mi * 16 + q * 4 + rr) * 64 + nb + 16 * j + l15] = yv[j][rr];
}

extern "C" void kernel_launch(void* const* d_in, const int* in_sizes, int n_in,
                              void* d_out, int out_size, void* d_ws, size_t ws_size,
                              hipStream_t stream) {
  const float* x   = (const float*)d_in[0];
  const float* y0  = (const float*)d_in[1];
  const float* W0  = (const float*)d_in[2];
  const float* b0  = (const float*)d_in[3];
  const float* g0  = (const float*)d_in[4];
  const float* be0 = (const float*)d_in[5];
  const float* W1  = (const float*)d_in[6];
  const float* b1  = (const float*)d_in[7];
  const float* g1  = (const float*)d_in[8];
  const float* be1 = (const float*)d_in[9];
  const float* W2  = (const float*)d_in[10];
  const float* b2  = (const float*)d_in[11];
  const float* g2  = (const float*)d_in[12];
  const float* be2 = (const float*)d_in[13];
  const float* wout = (const float*)d_in[14];
  u16* ws = (u16*)d_ws;         // needs 851,968 B
  float* out = (float*)d_out;

  prep_weights<<<1664, 256, 0, stream>>>(W0, W1, W2, ws);
  descent_kernel<<<512, 256, 0, stream>>>(x, y0, b0, g0, be0, b1, g1, be1,
                                          b2, g2, be2, wout, ws, out);
}

// Round 2
// 2307.926 us; speedup vs baseline: 1.4967x; 1.4967x over previous
//
#include <hip/hip_runtime.h>

// DescentPredictor: 50 SGD steps on y for E(x,y) = MLP([x;y]) energy.
// R2: int8 weights + activations (per-row scales) for all steady-state GEMMs
// via mfma_i32_16x16x64_i8 -> halves the weight fetch stream (the R1 bottleneck).

typedef unsigned short u16;
typedef u16 u16x4 __attribute__((ext_vector_type(4)));
typedef u16 u16x8 __attribute__((ext_vector_type(8)));
typedef float f32x4 __attribute__((ext_vector_type(4)));
typedef int i32x4 __attribute__((ext_vector_type(4)));
typedef __bf16 bf16x8 __attribute__((ext_vector_type(8)));

#define ITERS 50
#define EPSF 1e-5f
static constexpr float SCALE = 0.1f / 16384.0f;  // LR / B

// ---- ws byte offsets --------------------------------------------------------
#define OFF_W0X   0         // bf16 [256][512]
#define OFF_W0Y   262144    // i8 [256][64]
#define OFF_W0YT  278528    // i8 [64][256]
#define OFF_W1    294912    // i8 [256][256]
#define OFF_W1T   360448    // i8
#define OFF_W2    425984    // i8
#define OFF_W2T   491520    // i8
#define OFF_WSC   557056    // f32 [1344] row scales (order: W0Y,W0YT,W1,W1T,W2,W2T)

__device__ __forceinline__ float bf2f(u16 h) {
  union { unsigned int u; float f; } v; v.u = ((unsigned int)h) << 16; return v.f;
}
__device__ __forceinline__ u16 f2bf(float f) {
  union { float f; unsigned int u; } v; v.f = f;
  unsigned int u = v.u;
  return (u16)((u + 0x7FFFu + ((u >> 16) & 1u)) >> 16);  // RNE
}
__device__ __forceinline__ f32x4 mfma16(u16x8 a, u16x8 b, f32x4 c) {
  return __builtin_amdgcn_mfma_f32_16x16x32_bf16(
      __builtin_bit_cast(bf16x8, a), __builtin_bit_cast(bf16x8, b), c, 0, 0, 0);
}
__device__ __forceinline__ i32x4 mfma8(i32x4 a, i32x4 b, i32x4 c) {
  return __builtin_amdgcn_mfma_i32_16x16x64_i8(a, b, c, 0, 0, 0);
}
__device__ __forceinline__ int qpack4(const float* v, float qs) {
  int r = 0;
#pragma unroll
  for (int e = 0; e < 4; ++e) {
    float c = fmaxf(-127.f, fminf(127.f, v[e] * qs));
    int xi = __float2int_rn(c);
    r |= (xi & 255) << (8 * e);
  }
  return r;
}

// ---------------- prep: W0X f32 -> bf16 --------------------------------------
__global__ void prep_w0x(const float* __restrict__ W0, u16* __restrict__ dst) {
  int i = blockIdx.x * 256 + threadIdx.x;  // [256][512]
  if (i < 131072) dst[i] = f2bf(W0[(i >> 9) * 576 + (i & 511)]);
}

// ---------------- prep: i8 quant (one wave per output row) -------------------
__global__ void prep_quant(const float* __restrict__ W0, const float* __restrict__ W1,
                           const float* __restrict__ W2, char* __restrict__ ws) {
  int wid = blockIdx.x * 4 + (threadIdx.x >> 6);
  int lane = threadIdx.x & 63;
  float* sc = (float*)(ws + OFF_WSC);
  if (wid < 256) {  // W0Y row (64 cols, 1 val/lane)
    float v = W0[wid * 576 + 512 + lane];
    float mx = fabsf(v);
#pragma unroll
    for (int m = 1; m < 64; m <<= 1) mx = fmaxf(mx, __shfl_xor(mx, m));
    float qs = mx > 0.f ? 127.f / mx : 0.f;
    float c = fmaxf(-127.f, fminf(127.f, v * qs));
    ws[OFF_W0Y + wid * 64 + lane] = (char)__float2int_rn(c);
    if (lane == 0) sc[wid] = mx * (1.f / 127.f);
    return;
  }
  float v[4];
  char* dst;
  if (wid < 320) {         // W0YT row r = y-col r of W0
    int r = wid - 256;
#pragma unroll
    for (int e = 0; e < 4; ++e) v[e] = W0[(4 * lane + e) * 576 + 512 + r];
    dst = ws + OFF_W0YT + r * 256;
  } else if (wid < 576) {  // W1 row
    int r = wid - 320;
#pragma unroll
    for (int e = 0; e < 4; ++e) v[e] = W1[r * 256 + 4 * lane + e];
    dst = ws + OFF_W1 + r * 256;
  } else if (wid < 832) {  // W1T row
    int r = wid - 576;
#pragma unroll
    for (int e = 0; e < 4; ++e) v[e] = W1[(4 * lane + e) * 256 + r];
    dst = ws + OFF_W1T + r * 256;
  } else if (wid < 1088) { // W2 row
    int r = wid - 832;
#pragma unroll
    for (int e = 0; e < 4; ++e) v[e] = W2[r * 256 + 4 * lane + e];
    dst = ws + OFF_W2 + r * 256;
  } else {                 // W2T row
    int r = wid - 1088;
#pragma unroll
    for (int e = 0; e < 4; ++e) v[e] = W2[(4 * lane + e) * 256 + r];
    dst = ws + OFF_W2T + r * 256;
  }
  float mx = fmaxf(fmaxf(fabsf(v[0]), fabsf(v[1])), fmaxf(fabsf(v[2]), fabsf(v[3])));
#pragma unroll
  for (int m = 1; m < 64; m <<= 1) mx = fmaxf(mx, __shfl_xor(mx, m));
  float qs = mx > 0.f ? 127.f / mx : 0.f;
  ((int*)dst)[lane] = qpack4(v, qs);
  if (lane == 0) sc[wid] = mx * (1.f / 127.f);
}

// ---------------- i8 GEMM: per-wave 2 Mtiles x 4 Ntiles, K chunks of 64 ------
template <int KS, int LDB, int AST>
__device__ __forceinline__ void gemm8(const char* A, const char* __restrict__ Bg,
                                      i32x4 (&acc)[2][4], int w, int l15, int q) {
  const char* Ab = A + l15 * AST + q * 16;
  const char* Bb = Bg + (64 * w + l15) * LDB + q * 16;
#pragma unroll
  for (int ks = 0; ks < KS; ++ks) {
    i32x4 b[4];
#pragma unroll
    for (int j = 0; j < 4; ++j) b[j] = *(const i32x4*)(Bb + 16 * j * LDB + ks * 64);
#pragma unroll
    for (int i = 0; i < 2; ++i) {
      i32x4 a = *(const i32x4*)(Ab + 16 * i * AST + ks * 64);
#pragma unroll
      for (int j = 0; j < 4; ++j) acc[i][j] = mfma8(a, b[j], acc[i][j]);
    }
  }
}

// dy = dz0 @ W0y : out [32][64]; per-wave 1 Mtile x 2 Ntiles.
__device__ __forceinline__ void gemm_dy8(const char* A, const char* __restrict__ BT,
                                         i32x4 (&dy)[2], int mi, int nb, int l15, int q) {
  const char* Ab = A + (mi * 16 + l15) * 272 + q * 16;
  const char* B0 = BT + (nb + l15) * 256 + q * 16;
  const char* B1 = BT + (nb + 16 + l15) * 256 + q * 16;
#pragma unroll
  for (int ks = 0; ks < 4; ++ks) {
    i32x4 a = *(const i32x4*)(Ab + ks * 64);
    dy[0] = mfma8(a, *(const i32x4*)(B0 + ks * 64), dy[0]);
    dy[1] = mfma8(a, *(const i32x4*)(B1 + ks * 64), dy[1]);
  }
}

// dequant epilogue -> bf16 staging tile gT [32][264]
__device__ __forceinline__ void epi8(u16* gdst, const i32x4 (&acc)[2][4],
                                     const float* sRow, const float* sCol,
                                     int w, int l15, int q) {
#pragma unroll
  for (int i = 0; i < 2; ++i)
#pragma unroll
    for (int j = 0; j < 4; ++j) {
      int col = 64 * w + 16 * j + l15;
      float sc = sCol[col];
#pragma unroll
      for (int rr = 0; rr < 4; ++rr) {
        int row = 16 * i + 4 * q + rr;
        gdst[row * 264 + col] = f2bf((float)acc[i][j][rr] * sRow[row] * sc);
      }
    }
}

// ---------------- elementwise (8 threads/row, cols = 32u + 4cg + e) ----------
// fwd: read bf16 z from gT, LN+SiLU, write i8 zhat (+scale) and i8 act (+scale)
__device__ __forceinline__ void ew_fwd8(const u16* gIn, char* zqOut, float* szh,
                                        char* aOut, float* sAo, const float* bias,
                                        const float* g, const float* be,
                                        float* invOut, int t) {
  const int r = t >> 3, cg = t & 7;
  const u16* zp = gIn + r * 264 + 4 * cg;
  float z[32];
#pragma unroll
  for (int u = 0; u < 8; ++u) {
    u16x4 v = *(const u16x4*)(zp + 32 * u);
#pragma unroll
    for (int e = 0; e < 4; ++e) z[4 * u + e] = bf2f(v[e]);
  }
  if (bias) {
#pragma unroll
    for (int u = 0; u < 8; ++u) {
      f32x4 bv = *(const f32x4*)(bias + 32 * u + 4 * cg);
#pragma unroll
      for (int e = 0; e < 4; ++e) z[4 * u + e] += bv[e];
    }
  }
  float s = 0.f, ss = 0.f;
#pragma unroll
  for (int k = 0; k < 32; ++k) { s += z[k]; ss += z[k] * z[k]; }
  s += __shfl_xor(s, 1); ss += __shfl_xor(ss, 1);
  s += __shfl_xor(s, 2); ss += __shfl_xor(ss, 2);
  s += __shfl_xor(s, 4); ss += __shfl_xor(ss, 4);
  const float mu = s * (1.f / 256.f);
  const float var = ss * (1.f / 256.f) - mu * mu;
  const float inv = rsqrtf(var + EPSF);
  if (cg == 0) invOut[r] = inv;
  float a[32];
  float mzh = 0.f, ma = 0.f;
#pragma unroll
  for (int u = 0; u < 8; ++u) {
    f32x4 gv = *(const f32x4*)(g + 32 * u + 4 * cg);
    f32x4 bev = *(const f32x4*)(be + 32 * u + 4 * cg);
#pragma unroll
    for (int e = 0; e < 4; ++e) {
      const int k = 4 * u + e;
      float zn = (z[k] - mu) * inv;
      z[k] = zn;                       // z[] now holds zhat
      mzh = fmaxf(mzh, fabsf(zn));
      float uu = zn * gv[e] + bev[e];
      float av = uu / (1.f + __expf(-uu));  // SiLU
      a[k] = av;
      ma = fmaxf(ma, fabsf(av));
    }
  }
  mzh = fmaxf(mzh, __shfl_xor(mzh, 1)); ma = fmaxf(ma, __shfl_xor(ma, 1));
  mzh = fmaxf(mzh, __shfl_xor(mzh, 2)); ma = fmaxf(ma, __shfl_xor(ma, 2));
  mzh = fmaxf(mzh, __shfl_xor(mzh, 4)); ma = fmaxf(ma, __shfl_xor(ma, 4));
  float qz = mzh > 0.f ? 127.f / mzh : 0.f;
  float qa = ma > 0.f ? 127.f / ma : 0.f;
  if (cg == 0) { szh[r] = mzh * (1.f / 127.f); sAo[r] = ma * (1.f / 127.f); }
#pragma unroll
  for (int u = 0; u < 8; ++u) {
    *(int*)(zqOut + r * 272 + 32 * u + 4 * cg) = qpack4(&z[4 * u], qz);
    *(int*)(aOut + r * 272 + 32 * u + 4 * cg) = qpack4(&a[4 * u], qa);
  }
}

// layer2: fwd-LN + (da2 = Wout) + SiLU' + LN-bwd fused; gT z2 in -> i8 dz2 out.
__device__ __forceinline__ void ew_l2_8(const u16* gIn, char* dOut, float* sAo,
                                        const float* bias, const float* g,
                                        const float* be, const float* wo, int t) {
  const int r = t >> 3, cg = t & 7;
  const u16* zp = gIn + r * 264 + 4 * cg;
  float zh[32], dzh[32];
  float s = 0.f, ss = 0.f;
#pragma unroll
  for (int u = 0; u < 8; ++u) {
    u16x4 v = *(const u16x4*)(zp + 32 * u);
    f32x4 bv = *(const f32x4*)(bias + 32 * u + 4 * cg);
#pragma unroll
    for (int e = 0; e < 4; ++e) {
      float zz = bf2f(v[e]) + bv[e];
      zh[4 * u + e] = zz; s += zz; ss += zz * zz;
    }
  }
  s += __shfl_xor(s, 1); ss += __shfl_xor(ss, 1);
  s += __shfl_xor(s, 2); ss += __shfl_xor(ss, 2);
  s += __shfl_xor(s, 4); ss += __shfl_xor(ss, 4);
  const float mu = s * (1.f / 256.f);
  const float var = ss * (1.f / 256.f) - mu * mu;
  const float inv = rsqrtf(var + EPSF);
  float s1 = 0.f, s2 = 0.f;
#pragma unroll
  for (int u = 0; u < 8; ++u) {
    f32x4 gv = *(const f32x4*)(g + 32 * u + 4 * cg);
    f32x4 bev = *(const f32x4*)(be + 32 * u + 4 * cg);
    f32x4 wv = *(const f32x4*)(wo + 32 * u + 4 * cg);
#pragma unroll
    for (int e = 0; e < 4; ++e) {
      const int k = 4 * u + e;
      float zn = (zh[k] - mu) * inv;
      zh[k] = zn;
      float uu = zn * gv[e] + bev[e];
      float sg = 1.f / (1.f + __expf(-uu));
      float du = wv[e] * sg * (1.f + uu * (1.f - sg));
      float d = du * gv[e];
      dzh[k] = d; s1 += d; s2 += d * zn;
    }
  }
  s1 += __shfl_xor(s1, 1); s2 += __shfl_xor(s2, 1);
  s1 += __shfl_xor(s1, 2); s2 += __shfl_xor(s2, 2);
  s1 += __shfl_xor(s1, 4); s2 += __shfl_xor(s2, 4);
  const float m1 = s1 * (1.f / 256.f), m2 = s2 * (1.f / 256.f);
  float mx = 0.f;
#pragma unroll
  for (int k = 0; k < 32; ++k) {
    dzh[k] = inv * (dzh[k] - m1 - zh[k] * m2);
    mx = fmaxf(mx, fabsf(dzh[k]));
  }
  mx = fmaxf(mx, __shfl_xor(mx, 1));
  mx = fmaxf(mx, __shfl_xor(mx, 2));
  mx = fmaxf(mx, __shfl_xor(mx, 4));
  float qd = mx > 0.f ? 127.f / mx : 0.f;
  if (cg == 0) sAo[r] = mx * (1.f / 127.f);
#pragma unroll
  for (int u = 0; u < 8; ++u)
    *(int*)(dOut + r * 272 + 32 * u + 4 * cg) = qpack4(&dzh[4 * u], qd);
}

// bwd through SiLU+LN: gT da bf16 in, zhat i8 (+scale), -> i8 dz out (+scale)
__device__ __forceinline__ void ew_bwd8(const u16* gIn, const char* zq, const float* szh,
                                        const float* invArr, const float* g,
                                        const float* be, char* dOut, float* sAo, int t) {
  const int r = t >> 3, cg = t & 7;
  const u16* dp = gIn + r * 264 + 4 * cg;
  const char* zp = zq + r * 272 + 4 * cg;
  const float inv = invArr[r];
  const float szr = szh[r];
  float zh[32], dzh[32];
  float s1 = 0.f, s2 = 0.f;
#pragma unroll
  for (int u = 0; u < 8; ++u) {
    u16x4 dv = *(const u16x4*)(dp + 32 * u);
    int zi = *(const int*)(zp + 32 * u);
    f32x4 gv = *(const f32x4*)(g + 32 * u + 4 * cg);
    f32x4 bev = *(const f32x4*)(be + 32 * u + 4 * cg);
#pragma unroll
    for (int e = 0; e < 4; ++e) {
      const int k = 4 * u + e;
      float zn = (float)((signed char)(zi >> (8 * e))) * szr;
      float da = bf2f(dv[e]);
      float uu = zn * gv[e] + bev[e];
      float sg = 1.f / (1.f + __expf(-uu));
      float du = da * sg * (1.f + uu * (1.f - sg));
      float d = du * gv[e];
      zh[k] = zn; dzh[k] = d; s1 += d; s2 += d * zn;
    }
  }
  s1 += __shfl_xor(s1, 1); s2 += __shfl_xor(s2, 1);
  s1 += __shfl_xor(s1, 2); s2 += __shfl_xor(s2, 2);
  s1 += __shfl_xor(s1, 4); s2 += __shfl_xor(s2, 4);
  const float m1 = s1 * (1.f / 256.f), m2 = s2 * (1.f / 256.f);
  float mx = 0.f;
#pragma unroll
  for (int k = 0; k < 32; ++k) {
    dzh[k] = inv * (dzh[k] - m1 - zh[k] * m2);
    mx = fmaxf(mx, fabsf(dzh[k]));
  }
  mx = fmaxf(mx, __shfl_xor(mx, 1));
  mx = fmaxf(mx, __shfl_xor(mx, 2));
  mx = fmaxf(mx, __shfl_xor(mx, 4));
  float qd = mx > 0.f ? 127.f / mx : 0.f;
  if (cg == 0) sAo[r] = mx * (1.f / 127.f);
#pragma unroll
  for (int u = 0; u < 8; ++u)
    *(int*)(dOut + r * 272 + 32 * u + 4 * cg) = qpack4(&dzh[4 * u], qd);
}

// ---------------- main persistent kernel -------------------------------------
__global__ __launch_bounds__(256, 2) void descent_kernel(
    const float* __restrict__ x, const float* __restrict__ y0,
    const float* __restrict__ b0, const float* __restrict__ g0, const float* __restrict__ be0,
    const float* __restrict__ b1, const float* __restrict__ g1, const float* __restrict__ be1,
    const float* __restrict__ b2, const float* __restrict__ g2, const float* __restrict__ be2,
    const float* __restrict__ wout, const char* __restrict__ ws, float* __restrict__ out) {
  __shared__ __align__(16) char zq0[32 * 272];   // i8 zhat layer0
  __shared__ __align__(16) char zq1[32 * 272];   // i8 zhat layer1
  __shared__ __align__(16) char A8[32 * 272];    // i8 act / grad GEMM-A tile
  __shared__ __align__(16) u16 gT[32 * 264];     // bf16 staging (z / da)
  __shared__ __align__(16) char yb[32 * 80];     // i8 y tile
  __shared__ float params[9 * 256];              // g0 be0 g1 be1 g2 be2 b1 b2 wout
  __shared__ float wsc[1344];                    // weight row scales
  __shared__ float sA[32], szh0[32], szh1[32], sY[32];
  __shared__ float invs[2][32];
  __shared__ float smax[4 * 16];

  const int t = threadIdx.x;
  const int w = t >> 6, lane = t & 63, l15 = lane & 15, q = lane >> 4;
  const int rowbase = blockIdx.x * 32;

  const u16* W0X = (const u16*)(ws + OFF_W0X);
  const char* W0Yq = ws + OFF_W0Y;
  const char* W0YTq = ws + OFF_W0YT;
  const char* W1q = ws + OFF_W1;
  const char* W1Tq = ws + OFF_W1T;
  const char* W2q = ws + OFF_W2;
  const char* W2Tq = ws + OFF_W2T;
  const float* wscg = (const float*)(ws + OFF_WSC);

  params[0 * 256 + t] = g0[t];  params[1 * 256 + t] = be0[t];
  params[2 * 256 + t] = g1[t];  params[3 * 256 + t] = be1[t];
  params[4 * 256 + t] = g2[t];  params[5 * 256 + t] = be2[t];
  params[6 * 256 + t] = b1[t];  params[7 * 256 + t] = b2[t];
  params[8 * 256 + t] = wout[t];
#pragma unroll
  for (int k = 0; k < 6; ++k) {
    int idx = t + 256 * k;
    if (idx < 1344) wsc[idx] = wscg[idx];
  }

  // y master copy in registers (gemm_dy C/D layout)
  const int mi = w >> 1, nb = (w & 1) * 32;
  float yv[2][4];
#pragma unroll
  for (int j = 0; j < 2; ++j)
#pragma unroll
    for (int rr = 0; rr < 4; ++rr)
      yv[j][rr] = y0[(rowbase + mi * 16 + q * 4 + rr) * 64 + nb + 16 * j + l15];

  const f32x4 z4 = {0.f, 0.f, 0.f, 0.f};

  // Phase A: cR = x @ W0x^T + b0 (bf16 MFMA, one-time; stays in registers)
  f32x4 cR[2][4];
#pragma unroll
  for (int i = 0; i < 2; ++i)
#pragma unroll
    for (int j = 0; j < 4; ++j) cR[i][j] = z4;
  {
    const float* xp0 = x + (rowbase + l15) * 512 + q * 8;
    const u16* Bb = W0X + (64 * w + l15) * 512 + q * 8;
#pragma unroll 4
    for (int ks = 0; ks < 16; ++ks) {
      u16x8 b[4];
#pragma unroll
      for (int j = 0; j < 4; ++j) b[j] = *(const u16x8*)(Bb + 16 * j * 512 + ks * 32);
#pragma unroll
      for (int i = 0; i < 2; ++i) {
        const float* xp = xp0 + i * 16 * 512 + ks * 32;
        f32x4 x0 = *(const f32x4*)xp;
        f32x4 x1 = *(const f32x4*)(xp + 4);
        u16x8 a;
#pragma unroll
        for (int e = 0; e < 4; ++e) { a[e] = f2bf(x0[e]); a[4 + e] = f2bf(x1[e]); }
#pragma unroll
        for (int j = 0; j < 4; ++j) cR[i][j] = mfma16(a, b[j], cR[i][j]);
      }
    }
#pragma unroll
    for (int j = 0; j < 4; ++j) {
      float bb = b0[64 * w + 16 * j + l15];
#pragma unroll
      for (int i = 0; i < 2; ++i)
#pragma unroll
        for (int rr = 0; rr < 4; ++rr) cR[i][j][rr] += bb;
    }
  }
  __syncthreads();  // params/wsc ready

  for (int it = 0; it < ITERS; ++it) {
    // ---- y -> i8 tile with per-row scale (rowmax via shfl + partner wave) ----
    float mx[4];
#pragma unroll
    for (int rr = 0; rr < 4; ++rr)
      mx[rr] = fmaxf(fabsf(yv[0][rr]), fabsf(yv[1][rr]));
#pragma unroll
    for (int m = 1; m < 16; m <<= 1)
#pragma unroll
      for (int rr = 0; rr < 4; ++rr) mx[rr] = fmaxf(mx[rr], __shfl_xor(mx[rr], m));
    if (l15 == 0)
#pragma unroll
      for (int rr = 0; rr < 4; ++rr) smax[w * 16 + q * 4 + rr] = mx[rr];
    __syncthreads();
#pragma unroll
    for (int rr = 0; rr < 4; ++rr) {
      float m2 = fmaxf(mx[rr], smax[(w ^ 1) * 16 + q * 4 + rr]);
      float qy = m2 > 0.f ? 127.f / m2 : 0.f;
      int row = 16 * mi + 4 * q + rr;
      if (l15 == 0 && (w & 1) == 0) sY[row] = m2 * (1.f / 127.f);
#pragma unroll
      for (int j = 0; j < 2; ++j) {
        float c = fmaxf(-127.f, fminf(127.f, yv[j][rr] * qy));
        yb[row * 80 + nb + 16 * j + l15] = (char)__float2int_rn(c);
      }
    }
    __syncthreads();

    // ---- fwd layer0: z0 = c + y @ W0y^T ----
    i32x4 acc[2][4];
#pragma unroll
    for (int i = 0; i < 2; ++i)
#pragma unroll
      for (int j = 0; j < 4; ++j) acc[i][j] = (i32x4){0, 0, 0, 0};
    gemm8<1, 64, 80>(yb, W0Yq, acc, w, l15, q);
#pragma unroll
    for (int i = 0; i < 2; ++i)
#pragma unroll
      for (int j = 0; j < 4; ++j) {
        int col = 64 * w + 16 * j + l15;
        float sc = wsc[col];  // sW0Y
#pragma unroll
        for (int rr = 0; rr < 4; ++rr) {
          int row = 16 * i + 4 * q + rr;
          gT[row * 264 + col] = f2bf(cR[i][j][rr] + (float)acc[i][j][rr] * sY[row] * sc);
        }
      }
    __syncthreads();
    ew_fwd8(gT, zq0, szh0, A8, sA, nullptr, &params[0 * 256], &params[1 * 256],
            invs[0], t);
    __syncthreads();

    // ---- fwd layer1 ----
#pragma unroll
    for (int i = 0; i < 2; ++i)
#pragma unroll
      for (int j = 0; j < 4; ++j) acc[i][j] = (i32x4){0, 0, 0, 0};
    gemm8<4, 256, 272>(A8, W1q, acc, w, l15, q);
    epi8(gT, acc, sA, &wsc[320], w, l15, q);
    __syncthreads();
    ew_fwd8(gT, zq1, szh1, A8, sA, &params[6 * 256], &params[2 * 256],
            &params[3 * 256], invs[1], t);
    __syncthreads();

    // ---- fwd layer2 + fused top-grad + LN-bwd ----
#pragma unroll
    for (int i = 0; i < 2; ++i)
#pragma unroll
      for (int j = 0; j < 4; ++j) acc[i][j] = (i32x4){0, 0, 0, 0};
    gemm8<4, 256, 272>(A8, W2q, acc, w, l15, q);
    epi8(gT, acc, sA, &wsc[832], w, l15, q);
    __syncthreads();
    ew_l2_8(gT, A8, sA, &params[7 * 256], &params[4 * 256], &params[5 * 256],
            &params[8 * 256], t);
    __syncthreads();

    // ---- bwd layer2 GEMM: da1 = dz2 @ W2 ----
#pragma unroll
    for (int i = 0; i < 2; ++i)
#pragma unroll
      for (int j = 0; j < 4; ++j) acc[i][j] = (i32x4){0, 0, 0, 0};
    gemm8<4, 256, 272>(A8, W2Tq, acc, w, l15, q);
    epi8(gT, acc, sA, &wsc[1088], w, l15, q);
    __syncthreads();
    ew_bwd8(gT, zq1, szh1, invs[1], &params[2 * 256], &params[3 * 256], A8, sA, t);
    __syncthreads();

    // ---- bwd layer1 GEMM: da0 = dz1 @ W1 ----
#pragma unroll
    for (int i = 0; i < 2; ++i)
#pragma unroll
      for (int j = 0; j < 4; ++j) acc[i][j] = (i32x4){0, 0, 0, 0};
    gemm8<4, 256, 272>(A8, W1Tq, acc, w, l15, q);
    epi8(gT, acc, sA, &wsc[576], w, l15, q);
    __syncthreads();
    ew_bwd8(gT, zq0, szh0, invs[0], &params[0 * 256], &params[1 * 256], A8, sA, t);
    __syncthreads();

    // ---- bwd layer0: dy = dz0 @ W0y ; y -= (LR/B)*dy ----
    i32x4 dy[2] = {{0, 0, 0, 0}, {0, 0, 0, 0}};
    gemm_dy8(A8, W0YTq, dy, mi, nb, l15, q);
#pragma unroll
    for (int j = 0; j < 2; ++j)
#pragma unroll
      for (int rr = 0; rr < 4; ++rr) {
        int row = 16 * mi + 4 * q + rr;
        yv[j][rr] -= SCALE * (float)dy[j][rr] * sA[row] * wsc[256 + nb + 16 * j + l15];
      }
    // loop-head barrier orders next-iter writes
  }

#pragma unroll
  for (int j = 0; j < 2; ++j)
#pragma unroll
    for (int rr = 0; rr < 4; ++rr)
      out[(rowbase + mi * 16 + q * 4 + rr) * 64 + nb + 16 * j + l15] = yv[j][rr];
}

extern "C" void kernel_launch(void* const* d_in, const int* in_sizes, int n_in,
                              void* d_out, int out_size, void* d_ws, size_t ws_size,
                              hipStream_t stream) {
  const float* x   = (const float*)d_in[0];
  const float* y0  = (const float*)d_in[1];
  const float* W0  = (const float*)d_in[2];
  const float* b0  = (const float*)d_in[3];
  const float* g0  = (const float*)d_in[4];
  const float* be0 = (const float*)d_in[5];
  const float* W1  = (const float*)d_in[6];
  const float* b1  = (const float*)d_in[7];
  const float* g1  = (const float*)d_in[8];
  const float* be1 = (const float*)d_in[9];
  const float* W2  = (const float*)d_in[10];
  const float* b2  = (const float*)d_in[11];
  const float* g2  = (const float*)d_in[12];
  const float* be2 = (const float*)d_in[13];
  const float* wout = (const float*)d_in[14];
  char* ws = (char*)d_ws;  // needs 562,432 B
  float* out = (float*)d_out;

  prep_w0x<<<512, 256, 0, stream>>>(W0, (u16*)(ws + OFF_W0X));
  prep_quant<<<336, 256, 0, stream>>>(W0, W1, W2, ws);
  descent_kernel<<<512, 256, 0, stream>>>(x, y0, b0, g0, be0, b1, g1, be1,
                                          b2, g2, be2, wout, ws, out);
}